// Round 1
// baseline (311.488 us; speedup 1.0000x reference)
//
#include <hip/hip_runtime.h>
#include <math.h>

#define Bdim 64
#define Tdim 512
#define Sdim 400
#define Hdim 768
#define Ldim 9

// ---------------------------------------------------------------------------
// Kernel 1: per batch row, build
//   pos2tok[b,p] = token index t of the p-th valid token (cumsum(mask)-1)
//   wstart[b,s]  = exclusive prefix sum of ids_lens  (first valid-token pos of word s)
//   nvalid[b]    = total valid tokens in row b
// and zero the loss accumulators (ws is NOT re-poisoned between replays).
// ---------------------------------------------------------------------------
__global__ __launch_bounds__(Tdim) void setup_kernel(
    const int* __restrict__ attn, const int* __restrict__ ids_lens,
    int* __restrict__ pos2tok, int* __restrict__ wstart,
    int* __restrict__ nvalid, float* __restrict__ accum) {
  int b = blockIdx.x;
  int tid = threadIdx.x;
  __shared__ int sm[Tdim];

  if (b == 0 && tid < 2) accum[tid] = 0.0f;

  // phase 1: inclusive scan of attention mask (T = 512 = blockDim)
  int m = attn[b * Tdim + tid];
  sm[tid] = m;
  __syncthreads();
  for (int off = 1; off < Tdim; off <<= 1) {
    int v = (tid >= off) ? sm[tid - off] : 0;
    __syncthreads();
    sm[tid] += v;
    __syncthreads();
  }
  if (m) pos2tok[b * Tdim + sm[tid] - 1] = tid;
  if (tid == 0) nvalid[b] = sm[Tdim - 1];
  __syncthreads();

  // phase 2: inclusive scan of ids_lens (S = 400, pad to 512 with zeros)
  int len = (tid < Sdim) ? ids_lens[b * Sdim + tid] : 0;
  sm[tid] = len;
  __syncthreads();
  for (int off = 1; off < Tdim; off <<= 1) {
    int v = (tid >= off) ? sm[tid - off] : 0;
    __syncthreads();
    sm[tid] += v;
    __syncthreads();
  }
  if (tid < Sdim) wstart[b * Sdim + tid] = sm[tid] - len;  // exclusive prefix
}

// ---------------------------------------------------------------------------
// Kernel 2: one block per (b,s) word. Mean-pool token rows, project to L=9
// logits, argmax -> out, NLL -> atomic accumulators.
// ---------------------------------------------------------------------------
__global__ __launch_bounds__(256) void word_kernel(
    const float* __restrict__ enc, const float* __restrict__ W,
    const float* __restrict__ bias, const int* __restrict__ ids_lens,
    const int* __restrict__ label_ids, const int* __restrict__ pos2tok,
    const int* __restrict__ wstart, const int* __restrict__ nvalid,
    float* __restrict__ out, float* __restrict__ accum) {
  int bs = blockIdx.x;
  int b = bs / Sdim;
  int tid = threadIdx.x;
  int len = ids_lens[bs];

  float part[Ldim];
#pragma unroll
  for (int l = 0; l < Ldim; ++l) part[l] = 0.0f;

  if (len > 0) {
    int start = wstart[bs];
    int nv = nvalid[b];
    const int* p2t = pos2tok + b * Tdim;
    float s0 = 0.f, s1 = 0.f, s2 = 0.f;
    for (int j = 0; j < len; ++j) {
      int q = start + j;
      if (q >= nv) break;  // token doesn't exist (general-mask safety)
      int t = p2t[q];
      const float* row = enc + ((size_t)b * Tdim + t) * Hdim;
      s0 += row[tid];
      s1 += row[tid + 256];
      s2 += row[tid + 512];
    }
    float inv = 1.0f / (float)len;  // counts = max(ids_lens,1) = len here
    s0 *= inv; s1 *= inv; s2 *= inv;
    const float* w0 = W + (size_t)tid * Ldim;
    const float* w1 = W + (size_t)(tid + 256) * Ldim;
    const float* w2 = W + (size_t)(tid + 512) * Ldim;
#pragma unroll
    for (int l = 0; l < Ldim; ++l) part[l] = s0 * w0[l] + s1 * w1[l] + s2 * w2[l];
  }

  // block reduce: wave64 shuffle then cross-wave via LDS
#pragma unroll
  for (int l = 0; l < Ldim; ++l) {
    float v = part[l];
#pragma unroll
    for (int off = 32; off > 0; off >>= 1) v += __shfl_down(v, off, 64);
    part[l] = v;
  }
  __shared__ float red[4][Ldim];
  int wid = tid >> 6, lane = tid & 63;
  if (lane == 0) {
#pragma unroll
    for (int l = 0; l < Ldim; ++l) red[wid][l] = part[l];
  }
  __syncthreads();

  if (tid == 0) {
    float logits[Ldim];
#pragma unroll
    for (int l = 0; l < Ldim; ++l)
      logits[l] = red[0][l] + red[1][l] + red[2][l] + red[3][l] + bias[l];
    // argmax, first occurrence of max (matches jnp.argmax)
    int amax = 0;
    float mx = logits[0];
#pragma unroll
    for (int l = 1; l < Ldim; ++l)
      if (logits[l] > mx) { mx = logits[l]; amax = l; }
    out[1 + bs] = (float)amax;
    if (len > 0) {
      float se = 0.0f;
#pragma unroll
      for (int l = 0; l < Ldim; ++l) se += expf(logits[l] - mx);
      float lse = mx + logf(se);
      float nll = lse - logits[label_ids[bs]];
      atomicAdd(&accum[0], nll);
      atomicAdd(&accum[1], 1.0f);
    }
  }
}

// ---------------------------------------------------------------------------
// Kernel 3: loss = sum / count
// ---------------------------------------------------------------------------
__global__ void finalize_kernel(const float* __restrict__ accum,
                                float* __restrict__ out) {
  out[0] = accum[0] / accum[1];
}

extern "C" void kernel_launch(void* const* d_in, const int* in_sizes, int n_in,
                              void* d_out, int out_size, void* d_ws, size_t ws_size,
                              hipStream_t stream) {
  const float* enc      = (const float*)d_in[0];  // [B,T,H] f32
  const float* W        = (const float*)d_in[1];  // [H,L]   f32
  const float* bias     = (const float*)d_in[2];  // [L]     f32
  const int* attn       = (const int*)d_in[3];    // [B,T]   i32
  const int* ids_lens   = (const int*)d_in[4];    // [B,S]   i32
  const int* label_ids  = (const int*)d_in[5];    // [B,S]   i32
  // d_in[6] label_mask is recomputed from ids_lens>0 (avoids bool-dtype ambiguity)

  float* out = (float*)d_out;  // [1 + B*S]: loss, then argmax as float

  char* ws = (char*)d_ws;
  size_t off0 = 0;
  int* pos2tok = (int*)(ws + off0);            off0 += (size_t)Bdim * Tdim * sizeof(int);
  int* wstart  = (int*)(ws + off0);            off0 += (size_t)Bdim * Sdim * sizeof(int);
  int* nvalid  = (int*)(ws + off0);            off0 += 256;
  float* accum = (float*)(ws + off0);          // [2]: nll sum, valid-word count

  setup_kernel<<<Bdim, Tdim, 0, stream>>>(attn, ids_lens, pos2tok, wstart, nvalid, accum);
  word_kernel<<<Bdim * Sdim, 256, 0, stream>>>(enc, W, bias, ids_lens, label_ids,
                                               pos2tok, wstart, nvalid, out, accum);
  finalize_kernel<<<1, 1, 0, stream>>>(accum, out);
}

// Round 2
// 102.321 us; speedup vs baseline: 3.0442x; 3.0442x over previous
//
#include <hip/hip_runtime.h>
#include <math.h>

#define Bdim 64
#define Tdim 512
#define Sdim 400
#define Hdim 768
#define Ldim 9

// ---------------------------------------------------------------------------
// Kernel 1: per batch row, build
//   pos2tok[b,p] = token index t of the p-th valid token (cumsum(mask)-1)
//   wstart[b,s]  = exclusive prefix sum of ids_lens  (first valid-token pos of word s)
//   nvalid[b]    = total valid tokens in row b
// ---------------------------------------------------------------------------
__global__ __launch_bounds__(Tdim) void setup_kernel(
    const int* __restrict__ attn, const int* __restrict__ ids_lens,
    int* __restrict__ pos2tok, int* __restrict__ wstart,
    int* __restrict__ nvalid) {
  int b = blockIdx.x;
  int tid = threadIdx.x;
  __shared__ int sm[Tdim];

  // phase 1: inclusive scan of attention mask (T = 512 = blockDim)
  int m = attn[b * Tdim + tid];
  sm[tid] = m;
  __syncthreads();
  for (int off = 1; off < Tdim; off <<= 1) {
    int v = (tid >= off) ? sm[tid - off] : 0;
    __syncthreads();
    sm[tid] += v;
    __syncthreads();
  }
  if (m) pos2tok[b * Tdim + sm[tid] - 1] = tid;
  if (tid == 0) nvalid[b] = sm[Tdim - 1];
  __syncthreads();

  // phase 2: inclusive scan of ids_lens (S = 400, pad to 512 with zeros)
  int len = (tid < Sdim) ? ids_lens[b * Sdim + tid] : 0;
  sm[tid] = len;
  __syncthreads();
  for (int off = 1; off < Tdim; off <<= 1) {
    int v = (tid >= off) ? sm[tid - off] : 0;
    __syncthreads();
    sm[tid] += v;
    __syncthreads();
  }
  if (tid < Sdim) wstart[b * Sdim + tid] = sm[tid] - len;  // exclusive prefix
}

// ---------------------------------------------------------------------------
// Kernel 2: one block per (b,s) word. Mean-pool token rows, project to L=9
// logits, argmax -> out, per-word NLL -> nll_buf (NO global atomics:
// 51200 same-line atomicAdds serialized at L2 cost ~300us in R1).
// ---------------------------------------------------------------------------
__global__ __launch_bounds__(256) void word_kernel(
    const float* __restrict__ enc, const float* __restrict__ W,
    const float* __restrict__ bias, const int* __restrict__ ids_lens,
    const int* __restrict__ label_ids, const int* __restrict__ pos2tok,
    const int* __restrict__ wstart, const int* __restrict__ nvalid,
    float* __restrict__ out, float* __restrict__ nll_buf) {
  int bs = blockIdx.x;
  int b = bs / Sdim;
  int tid = threadIdx.x;
  int len = ids_lens[bs];

  float part[Ldim];
#pragma unroll
  for (int l = 0; l < Ldim; ++l) part[l] = 0.0f;

  if (len > 0) {
    int start = wstart[bs];
    int nv = nvalid[b];
    const int* p2t = pos2tok + b * Tdim;
    float s0 = 0.f, s1 = 0.f, s2 = 0.f;
    for (int j = 0; j < len; ++j) {
      int q = start + j;
      if (q >= nv) break;  // token doesn't exist (general-mask safety)
      int t = p2t[q];
      const float* row = enc + ((size_t)b * Tdim + t) * Hdim;
      s0 += row[tid];
      s1 += row[tid + 256];
      s2 += row[tid + 512];
    }
    float inv = 1.0f / (float)len;  // counts = max(ids_lens,1) = len here
    s0 *= inv; s1 *= inv; s2 *= inv;
    const float* w0 = W + (size_t)tid * Ldim;
    const float* w1 = W + (size_t)(tid + 256) * Ldim;
    const float* w2 = W + (size_t)(tid + 512) * Ldim;
#pragma unroll
    for (int l = 0; l < Ldim; ++l) part[l] = s0 * w0[l] + s1 * w1[l] + s2 * w2[l];
  }

  // block reduce: wave64 shuffle then cross-wave via LDS
#pragma unroll
  for (int l = 0; l < Ldim; ++l) {
    float v = part[l];
#pragma unroll
    for (int off = 32; off > 0; off >>= 1) v += __shfl_down(v, off, 64);
    part[l] = v;
  }
  __shared__ float red[4][Ldim];
  int wid = tid >> 6, lane = tid & 63;
  if (lane == 0) {
#pragma unroll
    for (int l = 0; l < Ldim; ++l) red[wid][l] = part[l];
  }
  __syncthreads();

  if (tid == 0) {
    float logits[Ldim];
#pragma unroll
    for (int l = 0; l < Ldim; ++l)
      logits[l] = red[0][l] + red[1][l] + red[2][l] + red[3][l] + bias[l];
    // argmax, first occurrence of max (matches jnp.argmax)
    int amax = 0;
    float mx = logits[0];
#pragma unroll
    for (int l = 1; l < Ldim; ++l)
      if (logits[l] > mx) { mx = logits[l]; amax = l; }
    out[1 + bs] = (float)amax;
    float nll = 0.0f;
    if (len > 0) {
      float se = 0.0f;
#pragma unroll
      for (int l = 0; l < Ldim; ++l) se += expf(logits[l] - mx);
      float lse = mx + logf(se);
      nll = lse - logits[label_ids[bs]];
    }
    nll_buf[bs] = nll;  // written unconditionally every call (deterministic)
  }
}

// ---------------------------------------------------------------------------
// Kernel 3: single-block reduction: loss = sum(nll) / count(ids_lens>0)
// ---------------------------------------------------------------------------
__global__ __launch_bounds__(256) void loss_kernel(
    const float* __restrict__ nll_buf, const int* __restrict__ ids_lens,
    float* __restrict__ out) {
  int tid = threadIdx.x;
  float s = 0.0f, c = 0.0f;
  for (int i = tid; i < Bdim * Sdim; i += 256) {
    s += nll_buf[i];
    c += (ids_lens[i] > 0) ? 1.0f : 0.0f;
  }
#pragma unroll
  for (int off = 32; off > 0; off >>= 1) {
    s += __shfl_down(s, off, 64);
    c += __shfl_down(c, off, 64);
  }
  __shared__ float ss[4], cc[4];
  int wid = tid >> 6, lane = tid & 63;
  if (lane == 0) { ss[wid] = s; cc[wid] = c; }
  __syncthreads();
  if (tid == 0) {
    float S = ss[0] + ss[1] + ss[2] + ss[3];
    float C = cc[0] + cc[1] + cc[2] + cc[3];
    out[0] = S / C;
  }
}

extern "C" void kernel_launch(void* const* d_in, const int* in_sizes, int n_in,
                              void* d_out, int out_size, void* d_ws, size_t ws_size,
                              hipStream_t stream) {
  const float* enc      = (const float*)d_in[0];  // [B,T,H] f32
  const float* W        = (const float*)d_in[1];  // [H,L]   f32
  const float* bias     = (const float*)d_in[2];  // [L]     f32
  const int* attn       = (const int*)d_in[3];    // [B,T]   i32
  const int* ids_lens   = (const int*)d_in[4];    // [B,S]   i32
  const int* label_ids  = (const int*)d_in[5];    // [B,S]   i32
  // d_in[6] label_mask is recomputed from ids_lens>0

  float* out = (float*)d_out;  // [1 + B*S]: loss, then argmax as float

  char* ws = (char*)d_ws;
  size_t off0 = 0;
  int* pos2tok   = (int*)(ws + off0);   off0 += (size_t)Bdim * Tdim * sizeof(int);
  int* wstart    = (int*)(ws + off0);   off0 += (size_t)Bdim * Sdim * sizeof(int);
  int* nvalid    = (int*)(ws + off0);   off0 += 256;
  float* nll_buf = (float*)(ws + off0); off0 += (size_t)Bdim * Sdim * sizeof(float);

  setup_kernel<<<Bdim, Tdim, 0, stream>>>(attn, ids_lens, pos2tok, wstart, nvalid);
  word_kernel<<<Bdim * Sdim, 256, 0, stream>>>(enc, W, bias, ids_lens, label_ids,
                                               pos2tok, wstart, nvalid, out, nll_buf);
  loss_kernel<<<1, 256, 0, stream>>>(nll_buf, ids_lens, out);
}

// Round 3
// 43.344 us; speedup vs baseline: 7.1864x; 2.3607x over previous
//
#include <hip/hip_runtime.h>
#include <math.h>

#define Bdim 64
#define Tdim 512
#define Sdim 400
#define Hdim 768
#define Ldim 9

#define PROJ_BLOCKS 768
#define PROJ_WAVES (PROJ_BLOCKS * 4)

// ---------------------------------------------------------------------------
// Kernel 1: per batch row, build
//   pos2tok[b,p] = token index t of the p-th valid token (cumsum(mask)-1)
//   wstart[b,s]  = exclusive prefix of ids_lens (first valid-token pos of word s)
//   nvalid[b]    = total valid tokens in row b
// ---------------------------------------------------------------------------
__global__ __launch_bounds__(Tdim) void setup_kernel(
    const int* __restrict__ attn, const int* __restrict__ ids_lens,
    int* __restrict__ pos2tok, int* __restrict__ wstart,
    int* __restrict__ nvalid) {
  int b = blockIdx.x;
  int tid = threadIdx.x;
  __shared__ int sm[Tdim];

  int m = attn[b * Tdim + tid];
  sm[tid] = m;
  __syncthreads();
  for (int off = 1; off < Tdim; off <<= 1) {
    int v = (tid >= off) ? sm[tid - off] : 0;
    __syncthreads();
    sm[tid] += v;
    __syncthreads();
  }
  if (m) pos2tok[b * Tdim + sm[tid] - 1] = tid;
  if (tid == 0) nvalid[b] = sm[Tdim - 1];
  __syncthreads();

  int len = (tid < Sdim) ? ids_lens[b * Sdim + tid] : 0;
  sm[tid] = len;
  __syncthreads();
  for (int off = 1; off < Tdim; off <<= 1) {
    int v = (tid >= off) ? sm[tid - off] : 0;
    __syncthreads();
    sm[tid] += v;
    __syncthreads();
  }
  if (tid < Sdim) wstart[b * Sdim + tid] = sm[tid] - len;
}

// ---------------------------------------------------------------------------
// Kernel 2: wave-per-valid-token projection. proj[b,q,:] = enc[b,pos2tok[b,q],:] @ W
// W fragment (108 floats) register-resident per lane; enc rows read as float4
// (coalesced 1KB/instr). Butterfly reduce across 64 lanes; lanes 0..8 write.
// ---------------------------------------------------------------------------
__global__ __launch_bounds__(256, 3) void proj_kernel(
    const float* __restrict__ enc, const float* __restrict__ W,
    const int* __restrict__ pos2tok, const int* __restrict__ nvalid,
    float* __restrict__ proj) {
  int tid = threadIdx.x;
  int lane = tid & 63;
  int wid = blockIdx.x * 4 + (tid >> 6);

  // per-lane W fragment: h = 4*lane + 256*k + j, k<3, j<4
  float wf[3][4][Ldim];
#pragma unroll
  for (int k = 0; k < 3; ++k)
#pragma unroll
    for (int j = 0; j < 4; ++j) {
      int h = 4 * lane + 256 * k + j;
#pragma unroll
      for (int l = 0; l < Ldim; ++l) wf[k][j][l] = W[(size_t)h * Ldim + l];
    }

  const float4* encf4 = (const float4*)enc;
  for (int p = wid; p < Bdim * Tdim; p += PROJ_WAVES) {
    int b = p >> 9;              // Tdim == 512
    int q = p & 511;
    if (q >= nvalid[b]) continue;            // wave-uniform skip
    int t = pos2tok[p];                       // p == b*Tdim + q
    const float4* row = encf4 + ((size_t)(b << 9) + t) * (Hdim / 4);
    float4 x0 = row[lane];
    float4 x1 = row[lane + 64];
    float4 x2 = row[lane + 128];

    float d[Ldim];
#pragma unroll
    for (int l = 0; l < Ldim; ++l) {
      d[l] = x0.x * wf[0][0][l] + x0.y * wf[0][1][l] +
             x0.z * wf[0][2][l] + x0.w * wf[0][3][l] +
             x1.x * wf[1][0][l] + x1.y * wf[1][1][l] +
             x1.z * wf[1][2][l] + x1.w * wf[1][3][l] +
             x2.x * wf[2][0][l] + x2.y * wf[2][1][l] +
             x2.z * wf[2][2][l] + x2.w * wf[2][3][l];
    }
    // full 64-lane butterfly: every lane ends with the row total
#pragma unroll
    for (int l = 0; l < Ldim; ++l) {
#pragma unroll
      for (int m = 32; m > 0; m >>= 1) d[l] += __shfl_xor(d[l], m, 64);
    }
    // extract d[lane] WITHOUT runtime register indexing (avoid scratch)
    float v = d[0];
#pragma unroll
    for (int l = 1; l < Ldim; ++l) v = (lane == l) ? d[l] : v;
    if (lane < Ldim) proj[(size_t)p * Ldim + lane] = v;
  }
}

// ---------------------------------------------------------------------------
// Kernel 3: thread-per-word. Sum 1..len proj rows (L2-resident), mean,
// +bias, argmax -> out, NLL -> block partial sums (no global atomics).
// ---------------------------------------------------------------------------
__global__ __launch_bounds__(256) void word_kernel(
    const float* __restrict__ proj, const float* __restrict__ bias,
    const int* __restrict__ ids_lens, const int* __restrict__ label_ids,
    const int* __restrict__ wstart, const int* __restrict__ nvalid,
    float* __restrict__ out, float2* __restrict__ partials) {
  int bs = blockIdx.x * 256 + threadIdx.x;   // grid covers exactly B*S
  int b = bs / Sdim;
  int len = ids_lens[bs];

  float s[Ldim];
#pragma unroll
  for (int l = 0; l < Ldim; ++l) s[l] = 0.0f;

  if (len > 0) {
    int start = wstart[bs];
    int nv = nvalid[b];
    for (int j = 0; j < len; ++j) {
      int q = start + j;
      if (q >= nv) break;
      const float* pr = proj + ((size_t)(b << 9) + q) * Ldim;
#pragma unroll
      for (int l = 0; l < Ldim; ++l) s[l] += pr[l];
    }
  }
  float inv = (len > 0) ? 1.0f / (float)len : 0.0f;
  float lg[Ldim];
#pragma unroll
  for (int l = 0; l < Ldim; ++l) lg[l] = s[l] * inv + bias[l];

  // argmax, first occurrence (matches jnp.argmax)
  int amax = 0;
  float mx = lg[0];
#pragma unroll
  for (int l = 1; l < Ldim; ++l)
    if (lg[l] > mx) { mx = lg[l]; amax = l; }
  out[1 + bs] = (float)amax;

  float nll = 0.0f, cnt = 0.0f;
  if (len > 0) {
    float se = 0.0f;
#pragma unroll
    for (int l = 0; l < Ldim; ++l) se += expf(lg[l] - mx);
    float lse = mx + logf(se);
    int lab = label_ids[bs];
    float ll = lg[0];
#pragma unroll
    for (int l = 1; l < Ldim; ++l) ll = (lab == l) ? lg[l] : ll;  // no runtime reg-index
    nll = lse - ll;
    cnt = 1.0f;
  }

  // block reduce (nll, cnt) -> partials[blockIdx]
#pragma unroll
  for (int off = 32; off > 0; off >>= 1) {
    nll += __shfl_down(nll, off, 64);
    cnt += __shfl_down(cnt, off, 64);
  }
  __shared__ float ss[4], cc[4];
  int wid = threadIdx.x >> 6, lane = threadIdx.x & 63;
  if (lane == 0) { ss[wid] = nll; cc[wid] = cnt; }
  __syncthreads();
  if (threadIdx.x == 0) {
    float2 pc;
    pc.x = ss[0] + ss[1] + ss[2] + ss[3];
    pc.y = cc[0] + cc[1] + cc[2] + cc[3];
    partials[blockIdx.x] = pc;
  }
}

// ---------------------------------------------------------------------------
// Kernel 4: sum 100 block partials -> loss
// ---------------------------------------------------------------------------
__global__ __launch_bounds__(128) void final_kernel(
    const float2* __restrict__ partials, int nblk, float* __restrict__ out) {
  int tid = threadIdx.x;
  float s = 0.0f, c = 0.0f;
  for (int i = tid; i < nblk; i += 128) {
    float2 pc = partials[i];
    s += pc.x;
    c += pc.y;
  }
#pragma unroll
  for (int off = 32; off > 0; off >>= 1) {
    s += __shfl_down(s, off, 64);
    c += __shfl_down(c, off, 64);
  }
  __shared__ float ss[2], cc[2];
  if ((tid & 63) == 0) { ss[tid >> 6] = s; cc[tid >> 6] = c; }
  __syncthreads();
  if (tid == 0) out[0] = (ss[0] + ss[1]) / (cc[0] + cc[1]);
}

extern "C" void kernel_launch(void* const* d_in, const int* in_sizes, int n_in,
                              void* d_out, int out_size, void* d_ws, size_t ws_size,
                              hipStream_t stream) {
  const float* enc      = (const float*)d_in[0];  // [B,T,H] f32
  const float* W        = (const float*)d_in[1];  // [H,L]   f32
  const float* bias     = (const float*)d_in[2];  // [L]     f32
  const int* attn       = (const int*)d_in[3];    // [B,T]   i32
  const int* ids_lens   = (const int*)d_in[4];    // [B,S]   i32
  const int* label_ids  = (const int*)d_in[5];    // [B,S]   i32
  // d_in[6] label_mask is recomputed from ids_lens>0

  float* out = (float*)d_out;  // [1 + B*S]: loss, then argmax as float

  char* ws = (char*)d_ws;
  size_t off0 = 0;
  int* pos2tok    = (int*)(ws + off0);    off0 += (size_t)Bdim * Tdim * sizeof(int);
  int* wstart     = (int*)(ws + off0);    off0 += (size_t)Bdim * Sdim * sizeof(int);
  int* nvalid     = (int*)(ws + off0);    off0 += 256;
  float* proj     = (float*)(ws + off0);  off0 += (size_t)Bdim * Tdim * Ldim * sizeof(float);
  float2* partials = (float2*)(ws + off0); off0 += 128 * sizeof(float2);

  int word_blocks = (Bdim * Sdim) / 256;  // 100, exact

  setup_kernel<<<Bdim, Tdim, 0, stream>>>(attn, ids_lens, pos2tok, wstart, nvalid);
  proj_kernel<<<PROJ_BLOCKS, 256, 0, stream>>>(enc, W, pos2tok, nvalid, proj);
  word_kernel<<<word_blocks, 256, 0, stream>>>(proj, bias, ids_lens, label_ids,
                                               wstart, nvalid, out, partials);
  final_kernel<<<1, 128, 0, stream>>>(partials, word_blocks, out);
}